// Round 6
// baseline (390.850 us; speedup 1.0000x reference)
//
#include <hip/hip_runtime.h>

#define N_NODES 50000
#define N_EDGES 1600000
#define MD 128
#define NH 8
#define DV 16
#define NS 32              // slot-counter shards (s = quad_index & 31)
#define SCAN_NBLK 196      // 196*256 = 50176 >= N_NODES
#define GEMM_NBLK 782      // ceil(50000/64)
#define SLOT_NBLK 1563     // ceil(400000/256)  (400000 = N_EDGES/4)

typedef unsigned int uint;
typedef unsigned short ushort;

__device__ __forceinline__ float bflo(uint u) { return __uint_as_float(u << 16); }
__device__ __forceinline__ float bfhi(uint u) { return __uint_as_float(u & 0xffff0000u); }
__device__ __forceinline__ ushort f2bf(float x) {
    uint b = __float_as_uint(x);
    b += 0x7fffu + ((b >> 16) & 1u);      // RNE
    return (ushort)(b >> 16);
}

// ---------------------------------------------------------------------------
// K0: combined transposed weight B[k][j]: j<128 -> Wv[j][k], j>=128 -> Ws[j-128][k]
// ---------------------------------------------------------------------------
__global__ void k0_prep(const float* __restrict__ Wv, const float* __restrict__ Ws,
                        float* __restrict__ B) {
    int idx = blockIdx.x * 256 + threadIdx.x;
    int k = idx >> 8;
    int j = idx & 255;
    B[idx] = (j < 128) ? Wv[j * 128 + k] : Ws[(j - 128) * 128 + k];
}

// ---------------------------------------------------------------------------
// K_FRONT: interleaved fusion of the GEMM and the sharded CSR slot pass.
//   b%3==0 -> GEMM block b/3 ; else slot block (b - b/3 - 1).
// Slot counters sharded 32x: deg[s][n], s = i & 31 -> ~16 RMWs/line instead
// of 512 (de-contends the per-line atomic serialization).
// ---------------------------------------------------------------------------
__global__ __launch_bounds__(256) void k_front(
    const float* __restrict__ inp, const float* __restrict__ B,
    const float* __restrict__ bias, const float* __restrict__ wsrc,
    const float* __restrict__ wtgt, ushort* __restrict__ value16,
    float* __restrict__ vs, float* __restrict__ vt, float* __restrict__ outp,
    const int* __restrict__ ei, int* __restrict__ deg, ushort* __restrict__ slot16) {
    __shared__ float sA[64 * 129];
    __shared__ float sB[32][256];

    const int b   = blockIdx.x;
    const int tid = threadIdx.x;

    if (b % 3 != 0) {
        // ---- slot pass: one returning atomic per edge, sharded counters ----
        int slotId = b - b / 3 - 1;
        int i = slotId * 256 + tid;               // 4 edges / thread
        if (i >= N_EDGES / 4) return;
        int s = i & (NS - 1);
        int* dsh = deg + s * N_NODES;
        int4 t = ((const int4*)(ei + N_EDGES))[i];
        ushort4 sl;
        sl.x = (ushort)atomicAdd(&dsh[t.x], 1);
        sl.y = (ushort)atomicAdd(&dsh[t.y], 1);
        sl.z = (ushort)atomicAdd(&dsh[t.z], 1);
        sl.w = (ushort)atomicAdd(&dsh[t.w], 1);
        ((ushort4*)slot16)[i] = sl;
        return;
    }

    // ---- GEMM block ----
    const int n0 = (b / 3) * 64;

    #pragma unroll
    for (int i = 0; i < 8; ++i) {
        int f4 = i * 256 + tid;
        int r  = f4 >> 5;
        int c4 = f4 & 31;
        float4 v = make_float4(0.f, 0.f, 0.f, 0.f);
        if (n0 + r < N_NODES) v = ((const float4*)(inp + (size_t)(n0 + r) * MD))[c4];
        sA[r * 129 + c4 * 4 + 0] = v.x;
        sA[r * 129 + c4 * 4 + 1] = v.y;
        sA[r * 129 + c4 * 4 + 2] = v.z;
        sA[r * 129 + c4 * 4 + 3] = v.w;
    }

    float acc[4][16];
    #pragma unroll
    for (int r = 0; r < 4; ++r)
        #pragma unroll
        for (int c = 0; c < 16; ++c) acc[r][c] = 0.f;

    const int r0 = (tid & 15) * 4;
    const int c0 = (tid >> 4) * 16;

    for (int kc = 0; kc < 4; ++kc) {
        #pragma unroll
        for (int i = 0; i < 8; ++i) {
            int f4 = i * 256 + tid;
            int kr = f4 >> 6;
            int c4 = f4 & 63;
            ((float4*)(&sB[kr][0]))[c4] =
                ((const float4*)(B + (size_t)(kc * 32 + kr) * 256))[c4];
        }
        __syncthreads();
        #pragma unroll 4
        for (int k = 0; k < 32; ++k) {
            int kk = kc * 32 + k;
            float a0 = sA[(r0 + 0) * 129 + kk];
            float a1 = sA[(r0 + 1) * 129 + kk];
            float a2 = sA[(r0 + 2) * 129 + kk];
            float a3 = sA[(r0 + 3) * 129 + kk];
            float bb[16];
            #pragma unroll
            for (int i = 0; i < 4; ++i) {
                float4 bv = ((const float4*)(&sB[k][c0]))[i];
                bb[i * 4 + 0] = bv.x; bb[i * 4 + 1] = bv.y;
                bb[i * 4 + 2] = bv.z; bb[i * 4 + 3] = bv.w;
            }
            #pragma unroll
            for (int c = 0; c < 16; ++c) {
                acc[0][c] = fmaf(a0, bb[c], acc[0][c]);
                acc[1][c] = fmaf(a1, bb[c], acc[1][c]);
                acc[2][c] = fmaf(a2, bb[c], acc[2][c]);
                acc[3][c] = fmaf(a3, bb[c], acc[3][c]);
            }
        }
        __syncthreads();
    }

    if (c0 < 128) {
        const int h = c0 >> 4;
        float wsr[16], wtr[16];
        #pragma unroll
        for (int i = 0; i < 16; ++i) { wsr[i] = wsrc[c0 + i]; wtr[i] = wtgt[c0 + i]; }
        #pragma unroll
        for (int r = 0; r < 4; ++r) {
            int n = n0 + r0 + r;
            if (n >= N_NODES) continue;
            union { ushort u[16]; uint4 q[2]; } pk;
            float s = 0.f, t = 0.f;
            #pragma unroll
            for (int i = 0; i < 16; ++i) {
                float v = acc[r][i];
                pk.u[i] = f2bf(v);
                s = fmaf(v, wsr[i], s);
                t = fmaf(v, wtr[i], t);
            }
            uint4* dst = (uint4*)(value16 + (size_t)n * MD + c0);
            dst[0] = pk.q[0]; dst[1] = pk.q[1];
            vs[n * NH + h] = s;
            vt[n * NH + h] = t;
        }
    } else {
        const int cc = c0 - 128;
        #pragma unroll
        for (int r = 0; r < 4; ++r) {
            int n = n0 + r0 + r;
            if (n >= N_NODES) continue;
            float4* dst = (float4*)(outp + (size_t)n * MD + cc);
            #pragma unroll
            for (int i = 0; i < 4; ++i)
                dst[i] = make_float4(acc[r][i * 4 + 0] + bias[cc + i * 4 + 0],
                                     acc[r][i * 4 + 1] + bias[cc + i * 4 + 1],
                                     acc[r][i * 4 + 2] + bias[cc + i * 4 + 2],
                                     acc[r][i * 4 + 3] + bias[cc + i * 4 + 3]);
        }
    }
}

// ---------------------------------------------------------------------------
// Scans: scan1 sums the 32 shards per node then block-scans; scan3 finalizes
// rowptr AND converts deg[s][n] in-place into per-(node,shard) base offsets.
// ---------------------------------------------------------------------------
__global__ void k_scan1(const int* __restrict__ deg, int* __restrict__ rowptr,
                        int* __restrict__ bsum) {
    __shared__ int s[256];
    int t = threadIdx.x, i = blockIdx.x * 256 + t;
    int v = 0;
    if (i < N_NODES) {
        #pragma unroll
        for (int sh = 0; sh < NS; ++sh) v += deg[sh * N_NODES + i];
    }
    s[t] = v;
    __syncthreads();
    #pragma unroll
    for (int off = 1; off < 256; off <<= 1) {
        int x = (t >= off) ? s[t - off] : 0;
        __syncthreads();
        s[t] += x;
        __syncthreads();
    }
    if (i < N_NODES) rowptr[i] = s[t] - v;
    if (t == 255) bsum[blockIdx.x] = s[255];
}

__global__ void k_scan2(const int* __restrict__ bsum, int* __restrict__ boff) {
    __shared__ int s[256];
    int t = threadIdx.x;
    int v = (t < SCAN_NBLK) ? bsum[t] : 0;
    s[t] = v;
    __syncthreads();
    #pragma unroll
    for (int off = 1; off < 256; off <<= 1) {
        int x = (t >= off) ? s[t - off] : 0;
        __syncthreads();
        s[t] += x;
        __syncthreads();
    }
    if (t < SCAN_NBLK) boff[t] = s[t] - v;
}

__global__ void k_scan3(int* __restrict__ rowptr, const int* __restrict__ boff,
                        int* __restrict__ deg) {
    int i = blockIdx.x * 256 + threadIdx.x;
    if (i < N_NODES) {
        int r = rowptr[i] + boff[blockIdx.x];
        rowptr[i] = r;
        int running = r;
        #pragma unroll
        for (int sh = 0; sh < NS; ++sh) {
            int c = deg[sh * N_NODES + i];
            deg[sh * N_NODES + i] = running;   // now the shard base
            running += c;
        }
    }
    if (i == 0) rowptr[N_NODES] = N_EDGES;
}

// ---------------------------------------------------------------------------
// K_PLACE: pos = deg[s][tgt] + slot ; csr[pos]=(src,eid); fdist[pos]=1/dist
// ---------------------------------------------------------------------------
__global__ void k_place(const int* __restrict__ ei, const int* __restrict__ deg,
                        const ushort* __restrict__ slot16, const float* __restrict__ dist,
                        int2* __restrict__ csr, float* __restrict__ fdist) {
    int i = blockIdx.x * 256 + threadIdx.x;            // 4 edges / thread
    if (i >= N_EDGES / 4) return;
    const int* dsh = deg + (i & (NS - 1)) * N_NODES;
    int4 s = ((const int4*)ei)[i];
    int4 t = ((const int4*)(ei + N_EDGES))[i];
    ushort4 sl = ((const ushort4*)slot16)[i];
    float4 d = ((const float4*)dist)[i];
    int e = i * 4;
    int p0 = dsh[t.x] + sl.x; csr[p0] = make_int2(s.x, e + 0); fdist[p0] = 1.f / d.x;
    int p1 = dsh[t.y] + sl.y; csr[p1] = make_int2(s.y, e + 1); fdist[p1] = 1.f / d.y;
    int p2 = dsh[t.z] + sl.z; csr[p2] = make_int2(s.z, e + 2); fdist[p2] = 1.f / d.z;
    int p3 = dsh[t.w] + sl.w; csr[p3] = make_int2(s.w, e + 3); fdist[p3] = 1.f / d.w;
}

// ---------------------------------------------------------------------------
// K_GATHER: one wave per target node. Lane l: es = l>>3, h = l&7.
// ---------------------------------------------------------------------------
__global__ __launch_bounds__(256) void k_gather(
    const int2* __restrict__ csr, const int* __restrict__ rowptr,
    const float* __restrict__ fdist, const float* __restrict__ vs,
    const float* __restrict__ vt, const ushort* __restrict__ value16,
    float* __restrict__ outp, float* __restrict__ attn_out) {
    int n = (blockIdx.x * 256 + threadIdx.x) >> 6;
    if (n >= N_NODES) return;
    int l  = threadIdx.x & 63;
    int es = l >> 3;
    int h  = l & 7;
    int start = rowptr[n], end = rowptr[n + 1];
    float vt_h = vt[n * NH + h];

    // Phase A: denominator
    float dsum = 0.f;
    for (int p = start + es; p < end; p += 8) {
        int2 se = csr[p];
        float s = vs[se.x * NH + h] + vt_h;
        s = (s >= 0.f) ? s : 0.2f * s;
        dsum += __expf(s) * fdist[p];
    }
    dsum += __shfl_xor(dsum, 8, 64);
    dsum += __shfl_xor(dsum, 16, 64);
    dsum += __shfl_xor(dsum, 32, 64);
    float rden = 1.f / dsum;

    // Phase B
    float acc[16];
    #pragma unroll
    for (int i = 0; i < 16; ++i) acc[i] = 0.f;
    for (int p = start + es; p < end; p += 8) {
        int2 se = csr[p];
        float s = vs[se.x * NH + h] + vt_h;
        s = (s >= 0.f) ? s : 0.2f * s;
        float attn = __expf(s) * fdist[p] * rden;
        attn_out[(size_t)se.y * NH + h] = attn;
        const uint4* vrow = (const uint4*)(value16 + (size_t)se.x * MD + h * DV);
        uint4 q0 = vrow[0], q1 = vrow[1];
        acc[0]  += attn * bflo(q0.x); acc[1]  += attn * bfhi(q0.x);
        acc[2]  += attn * bflo(q0.y); acc[3]  += attn * bfhi(q0.y);
        acc[4]  += attn * bflo(q0.z); acc[5]  += attn * bfhi(q0.z);
        acc[6]  += attn * bflo(q0.w); acc[7]  += attn * bfhi(q0.w);
        acc[8]  += attn * bflo(q1.x); acc[9]  += attn * bfhi(q1.x);
        acc[10] += attn * bflo(q1.y); acc[11] += attn * bfhi(q1.y);
        acc[12] += attn * bflo(q1.z); acc[13] += attn * bfhi(q1.z);
        acc[14] += attn * bflo(q1.w); acc[15] += attn * bfhi(q1.w);
    }
    #pragma unroll
    for (int i = 0; i < 16; ++i) {
        acc[i] += __shfl_xor(acc[i], 8, 64);
        acc[i] += __shfl_xor(acc[i], 16, 64);
        acc[i] += __shfl_xor(acc[i], 32, 64);
    }
    if (es == 0) {
        float4* orow = (float4*)(outp + (size_t)n * MD + h * DV);
        #pragma unroll
        for (int i = 0; i < 4; ++i) {
            float4 o = orow[i];
            o.x += acc[i * 4 + 0]; o.y += acc[i * 4 + 1];
            o.z += acc[i * 4 + 2]; o.w += acc[i * 4 + 3];
            orow[i] = o;
        }
    }
}

// ---------------------------------------------------------------------------
extern "C" void kernel_launch(void* const* d_in, const int* in_sizes, int n_in,
                              void* d_out, int out_size, void* d_ws, size_t ws_size,
                              hipStream_t stream) {
    const float* inp  = (const float*)d_in[0];
    const int*   ei   = (const int*)d_in[1];
    const float* dist = (const float*)d_in[2];
    const float* Wv   = (const float*)d_in[4];
    const float* wsrc = (const float*)d_in[5];
    const float* wtgt = (const float*)d_in[6];
    const float* Ws   = (const float*)d_in[7];
    const float* bias = (const float*)d_in[8];

    float* outp = (float*)d_out;
    float* attn = outp + (size_t)N_NODES * MD;

    float*  wsf     = (float*)d_ws;
    float*  B       = wsf;                                     // 128 KB
    float*  vs      = B + 32768;                               // 1.6 MB
    float*  vt      = vs + N_NODES * NH;                       // 1.6 MB
    ushort* value16 = (ushort*)(vt + N_NODES * NH);            // 12.8 MB
    int2*   csr     = (int2*)(value16 + (size_t)N_NODES * MD); // 12.8 MB
    float*  fdist   = (float*)(csr + N_EDGES);                 // 6.4 MB
    ushort* slot16  = (ushort*)(fdist + N_EDGES);              // 3.2 MB
    int*    deg     = (int*)(slot16 + N_EDGES);                // NS*N = 6.4 MB
    int*    rowptr  = deg + NS * N_NODES;                      // 50001
    int*    bsum    = rowptr + N_NODES + 1;                    // 256
    int*    boff    = bsum + 256;                              // 256

    hipMemsetAsync(deg, 0, (size_t)NS * N_NODES * sizeof(int), stream);

    k0_prep<<<128, 256, 0, stream>>>(Wv, Ws, B);
    k_front<<<GEMM_NBLK + SLOT_NBLK, 256, 0, stream>>>(
        inp, B, bias, wsrc, wtgt, value16, vs, vt, outp, ei, deg, slot16);
    k_scan1<<<SCAN_NBLK, 256, 0, stream>>>(deg, rowptr, bsum);
    k_scan2<<<1, 256, 0, stream>>>(bsum, boff);
    k_scan3<<<SCAN_NBLK, 256, 0, stream>>>(rowptr, boff, deg);
    k_place<<<(N_EDGES / 4 + 255) / 256, 256, 0, stream>>>(ei, deg, slot16,
                                                           dist, csr, fdist);
    k_gather<<<(N_NODES + 3) / 4, 256, 0, stream>>>(csr, rowptr, fdist, vs, vt,
                                                    value16, outp, attn);
}

// Round 7
// 359.713 us; speedup vs baseline: 1.0866x; 1.0866x over previous
//
#include <hip/hip_runtime.h>

#define N_NODES 50000
#define N_EDGES 1600000
#define MD 128
#define NH 8
#define DV 16
#define SCAN_NBLK 196      // 196*256 = 50176 >= N_NODES
#define GEMM_NBLK 782      // ceil(50000/64)
#define SLOT_NBLK 1563     // ceil(400000/256)  (400000 = N_EDGES/4)

typedef unsigned int uint;
typedef unsigned short ushort;

__device__ __forceinline__ float bflo(uint u) { return __uint_as_float(u << 16); }
__device__ __forceinline__ float bfhi(uint u) { return __uint_as_float(u & 0xffff0000u); }
__device__ __forceinline__ ushort f2bf(float x) {
    uint b = __float_as_uint(x);
    b += 0x7fffu + ((b >> 16) & 1u);      // RNE
    return (ushort)(b >> 16);
}

// ---------------------------------------------------------------------------
// K0: build combined transposed weight B[k][j] AND zero deg (memset fused).
// ---------------------------------------------------------------------------
__global__ void k0_prep(const float* __restrict__ Wv, const float* __restrict__ Ws,
                        float* __restrict__ B, int* __restrict__ deg) {
    int idx = blockIdx.x * 256 + threadIdx.x;
    if (idx < 128 * 256) {
        int k = idx >> 8;
        int j = idx & 255;
        B[idx] = (j < 128) ? Wv[j * 128 + k] : Ws[(j - 128) * 128 + k];
    }
    if (idx < N_NODES) deg[idx] = 0;
}

// ---------------------------------------------------------------------------
// K_FRONT: interleaved fusion of the GEMM and the CSR slot pass.
//   b%3==0 -> GEMM block b/3 ; else slot block.
// LDS = 49.4 KB (sB chunks of 16 k-rows) -> 3 blocks/CU.
// ---------------------------------------------------------------------------
__global__ __launch_bounds__(256) void k_front(
    const float* __restrict__ inp, const float* __restrict__ B,
    const float* __restrict__ bias, const float* __restrict__ wsrc,
    const float* __restrict__ wtgt, ushort* __restrict__ value16,
    float* __restrict__ vs, float* __restrict__ vt, float* __restrict__ outp,
    const int* __restrict__ ei, int* __restrict__ deg, ushort* __restrict__ slot16) {
    __shared__ float sA[64 * 129];     // 33.0 KB
    __shared__ float sB[16][256];      // 16.4 KB

    const int b   = blockIdx.x;
    const int tid = threadIdx.x;

    if (b % 3 != 0) {
        // ---- slot pass: one returning atomic per edge ----
        int slotId = b - b / 3 - 1;
        int i = slotId * 256 + tid;               // 4 edges / thread
        if (i >= N_EDGES / 4) return;
        int4 t = ((const int4*)(ei + N_EDGES))[i];
        ushort4 sl;
        sl.x = (ushort)atomicAdd(&deg[t.x], 1);
        sl.y = (ushort)atomicAdd(&deg[t.y], 1);
        sl.z = (ushort)atomicAdd(&deg[t.z], 1);
        sl.w = (ushort)atomicAdd(&deg[t.w], 1);
        ((ushort4*)slot16)[i] = sl;
        return;
    }

    // ---- GEMM block ----
    const int n0 = (b / 3) * 64;

    #pragma unroll
    for (int i = 0; i < 8; ++i) {
        int f4 = i * 256 + tid;
        int r  = f4 >> 5;
        int c4 = f4 & 31;
        float4 v = make_float4(0.f, 0.f, 0.f, 0.f);
        if (n0 + r < N_NODES) v = ((const float4*)(inp + (size_t)(n0 + r) * MD))[c4];
        sA[r * 129 + c4 * 4 + 0] = v.x;
        sA[r * 129 + c4 * 4 + 1] = v.y;
        sA[r * 129 + c4 * 4 + 2] = v.z;
        sA[r * 129 + c4 * 4 + 3] = v.w;
    }

    float acc[4][16];
    #pragma unroll
    for (int r = 0; r < 4; ++r)
        #pragma unroll
        for (int c = 0; c < 16; ++c) acc[r][c] = 0.f;

    const int r0 = (tid & 15) * 4;
    const int c0 = (tid >> 4) * 16;

    for (int kc = 0; kc < 8; ++kc) {
        // stage 16 k-rows x 256 cols
        #pragma unroll
        for (int i = 0; i < 4; ++i) {
            int f4 = i * 256 + tid;       // 0..1023
            int kr = f4 >> 6;             // 64 float4 per row
            int c4 = f4 & 63;
            ((float4*)(&sB[kr][0]))[c4] =
                ((const float4*)(B + (size_t)(kc * 16 + kr) * 256))[c4];
        }
        __syncthreads();
        #pragma unroll 4
        for (int k = 0; k < 16; ++k) {
            int kk = kc * 16 + k;
            float a0 = sA[(r0 + 0) * 129 + kk];
            float a1 = sA[(r0 + 1) * 129 + kk];
            float a2 = sA[(r0 + 2) * 129 + kk];
            float a3 = sA[(r0 + 3) * 129 + kk];
            float bb[16];
            #pragma unroll
            for (int i = 0; i < 4; ++i) {
                float4 bv = ((const float4*)(&sB[k][c0]))[i];
                bb[i * 4 + 0] = bv.x; bb[i * 4 + 1] = bv.y;
                bb[i * 4 + 2] = bv.z; bb[i * 4 + 3] = bv.w;
            }
            #pragma unroll
            for (int c = 0; c < 16; ++c) {
                acc[0][c] = fmaf(a0, bb[c], acc[0][c]);
                acc[1][c] = fmaf(a1, bb[c], acc[1][c]);
                acc[2][c] = fmaf(a2, bb[c], acc[2][c]);
                acc[3][c] = fmaf(a3, bb[c], acc[3][c]);
            }
        }
        __syncthreads();
    }

    if (c0 < 128) {
        const int h = c0 >> 4;
        float wsr[16], wtr[16];
        #pragma unroll
        for (int i = 0; i < 16; ++i) { wsr[i] = wsrc[c0 + i]; wtr[i] = wtgt[c0 + i]; }
        #pragma unroll
        for (int r = 0; r < 4; ++r) {
            int n = n0 + r0 + r;
            if (n >= N_NODES) continue;
            union { ushort u[16]; uint4 q[2]; } pk;
            float s = 0.f, t = 0.f;
            #pragma unroll
            for (int i = 0; i < 16; ++i) {
                float v = acc[r][i];
                pk.u[i] = f2bf(v);
                s = fmaf(v, wsr[i], s);
                t = fmaf(v, wtr[i], t);
            }
            uint4* dst = (uint4*)(value16 + (size_t)n * MD + c0);
            dst[0] = pk.q[0]; dst[1] = pk.q[1];
            vs[n * NH + h] = s;
            vt[n * NH + h] = t;
        }
    } else {
        const int cc = c0 - 128;
        #pragma unroll
        for (int r = 0; r < 4; ++r) {
            int n = n0 + r0 + r;
            if (n >= N_NODES) continue;
            float4* dst = (float4*)(outp + (size_t)n * MD + cc);
            #pragma unroll
            for (int i = 0; i < 4; ++i)
                dst[i] = make_float4(acc[r][i * 4 + 0] + bias[cc + i * 4 + 0],
                                     acc[r][i * 4 + 1] + bias[cc + i * 4 + 1],
                                     acc[r][i * 4 + 2] + bias[cc + i * 4 + 2],
                                     acc[r][i * 4 + 3] + bias[cc + i * 4 + 3]);
        }
    }
}

// ---------------------------------------------------------------------------
// Scans (exclusive prefix over deg -> rowptr)
// ---------------------------------------------------------------------------
__global__ void k_scan1(const int* __restrict__ deg, int* __restrict__ rowptr,
                        int* __restrict__ bsum) {
    __shared__ int s[256];
    int t = threadIdx.x, i = blockIdx.x * 256 + t;
    int v = (i < N_NODES) ? deg[i] : 0;
    s[t] = v;
    __syncthreads();
    #pragma unroll
    for (int off = 1; off < 256; off <<= 1) {
        int x = (t >= off) ? s[t - off] : 0;
        __syncthreads();
        s[t] += x;
        __syncthreads();
    }
    if (i < N_NODES) rowptr[i] = s[t] - v;
    if (t == 255) bsum[blockIdx.x] = s[255];
}

__global__ void k_scan2(const int* __restrict__ bsum, int* __restrict__ boff) {
    __shared__ int s[256];
    int t = threadIdx.x;
    int v = (t < SCAN_NBLK) ? bsum[t] : 0;
    s[t] = v;
    __syncthreads();
    #pragma unroll
    for (int off = 1; off < 256; off <<= 1) {
        int x = (t >= off) ? s[t - off] : 0;
        __syncthreads();
        s[t] += x;
        __syncthreads();
    }
    if (t < SCAN_NBLK) boff[t] = s[t] - v;
}

__global__ void k_scan3(int* __restrict__ rowptr, const int* __restrict__ boff) {
    int i = blockIdx.x * 256 + threadIdx.x;
    if (i < N_NODES) rowptr[i] += boff[blockIdx.x];
    if (i == 0) rowptr[N_NODES] = N_EDGES;
}

// ---------------------------------------------------------------------------
// K_PLACE: pos = rowptr[tgt] + slot; csr4[pos] = {src, eid, bits(1/dist), 0}
// Single 16B scattered store per edge (was 8B + 4B to two regions).
// ---------------------------------------------------------------------------
__global__ void k_place(const int* __restrict__ ei, const int* __restrict__ rowptr,
                        const ushort* __restrict__ slot16, const float* __restrict__ dist,
                        int4* __restrict__ csr4) {
    int i = blockIdx.x * 256 + threadIdx.x;            // 4 edges / thread
    if (i >= N_EDGES / 4) return;
    int4 s = ((const int4*)ei)[i];
    int4 t = ((const int4*)(ei + N_EDGES))[i];
    ushort4 sl = ((const ushort4*)slot16)[i];
    float4 d = ((const float4*)dist)[i];
    int e = i * 4;
    csr4[rowptr[t.x] + sl.x] = make_int4(s.x, e + 0, __float_as_int(1.f / d.x), 0);
    csr4[rowptr[t.y] + sl.y] = make_int4(s.y, e + 1, __float_as_int(1.f / d.y), 0);
    csr4[rowptr[t.z] + sl.z] = make_int4(s.z, e + 2, __float_as_int(1.f / d.z), 0);
    csr4[rowptr[t.w] + sl.w] = make_int4(s.w, e + 3, __float_as_int(1.f / d.w), 0);
}

// ---------------------------------------------------------------------------
// K_GATHER: one wave per target node. Lane l: es = l>>3, h = l&7.
// 2x unrolled: two independent csr/value loads in flight per lane.
// ---------------------------------------------------------------------------
__global__ __launch_bounds__(256) void k_gather(
    const int4* __restrict__ csr4, const int* __restrict__ rowptr,
    const float* __restrict__ vs, const float* __restrict__ vt,
    const ushort* __restrict__ value16,
    float* __restrict__ outp, float* __restrict__ attn_out) {
    int n = (blockIdx.x * 256 + threadIdx.x) >> 6;
    if (n >= N_NODES) return;
    int l  = threadIdx.x & 63;
    int es = l >> 3;
    int h  = l & 7;
    int start = rowptr[n], end = rowptr[n + 1];
    float vt_h = vt[n * NH + h];

    // Phase A: denominator
    float dsum = 0.f;
    int p = start + es;
    for (; p + 8 < end; p += 16) {
        int4 a = csr4[p];
        int4 b = csr4[p + 8];
        float sa = vs[a.x * NH + h] + vt_h;
        float sb = vs[b.x * NH + h] + vt_h;
        sa = (sa >= 0.f) ? sa : 0.2f * sa;
        sb = (sb >= 0.f) ? sb : 0.2f * sb;
        dsum += __expf(sa) * __int_as_float(a.z) + __expf(sb) * __int_as_float(b.z);
    }
    if (p < end) {
        int4 a = csr4[p];
        float sa = vs[a.x * NH + h] + vt_h;
        sa = (sa >= 0.f) ? sa : 0.2f * sa;
        dsum += __expf(sa) * __int_as_float(a.z);
    }
    dsum += __shfl_xor(dsum, 8, 64);
    dsum += __shfl_xor(dsum, 16, 64);
    dsum += __shfl_xor(dsum, 32, 64);
    float rden = 1.f / dsum;

    // Phase B
    float acc[16];
    #pragma unroll
    for (int i = 0; i < 16; ++i) acc[i] = 0.f;
    p = start + es;
    for (; p + 8 < end; p += 16) {
        int4 a = csr4[p];
        int4 b = csr4[p + 8];
        const uint4* va = (const uint4*)(value16 + (size_t)a.x * MD + h * DV);
        const uint4* vb = (const uint4*)(value16 + (size_t)b.x * MD + h * DV);
        uint4 qa0 = va[0], qa1 = va[1];
        uint4 qb0 = vb[0], qb1 = vb[1];
        float sa = vs[a.x * NH + h] + vt_h;
        float sb = vs[b.x * NH + h] + vt_h;
        sa = (sa >= 0.f) ? sa : 0.2f * sa;
        sb = (sb >= 0.f) ? sb : 0.2f * sb;
        float aa = __expf(sa) * __int_as_float(a.z) * rden;
        float ab = __expf(sb) * __int_as_float(b.z) * rden;
        attn_out[(size_t)a.y * NH + h] = aa;
        attn_out[(size_t)b.y * NH + h] = ab;
        acc[0]  += aa * bflo(qa0.x) + ab * bflo(qb0.x);
        acc[1]  += aa * bfhi(qa0.x) + ab * bfhi(qb0.x);
        acc[2]  += aa * bflo(qa0.y) + ab * bflo(qb0.y);
        acc[3]  += aa * bfhi(qa0.y) + ab * bfhi(qb0.y);
        acc[4]  += aa * bflo(qa0.z) + ab * bflo(qb0.z);
        acc[5]  += aa * bfhi(qa0.z) + ab * bfhi(qb0.z);
        acc[6]  += aa * bflo(qa0.w) + ab * bflo(qb0.w);
        acc[7]  += aa * bfhi(qa0.w) + ab * bfhi(qb0.w);
        acc[8]  += aa * bflo(qa1.x) + ab * bflo(qb1.x);
        acc[9]  += aa * bfhi(qa1.x) + ab * bfhi(qb1.x);
        acc[10] += aa * bflo(qa1.y) + ab * bflo(qb1.y);
        acc[11] += aa * bfhi(qa1.y) + ab * bfhi(qb1.y);
        acc[12] += aa * bflo(qa1.z) + ab * bflo(qb1.z);
        acc[13] += aa * bfhi(qa1.z) + ab * bfhi(qb1.z);
        acc[14] += aa * bflo(qa1.w) + ab * bflo(qb1.w);
        acc[15] += aa * bfhi(qa1.w) + ab * bfhi(qb1.w);
    }
    if (p < end) {
        int4 a = csr4[p];
        const uint4* va = (const uint4*)(value16 + (size_t)a.x * MD + h * DV);
        uint4 qa0 = va[0], qa1 = va[1];
        float sa = vs[a.x * NH + h] + vt_h;
        sa = (sa >= 0.f) ? sa : 0.2f * sa;
        float aa = __expf(sa) * __int_as_float(a.z) * rden;
        attn_out[(size_t)a.y * NH + h] = aa;
        acc[0]  += aa * bflo(qa0.x); acc[1]  += aa * bfhi(qa0.x);
        acc[2]  += aa * bflo(qa0.y); acc[3]  += aa * bfhi(qa0.y);
        acc[4]  += aa * bflo(qa0.z); acc[5]  += aa * bfhi(qa0.z);
        acc[6]  += aa * bflo(qa0.w); acc[7]  += aa * bfhi(qa0.w);
        acc[8]  += aa * bflo(qa1.x); acc[9]  += aa * bfhi(qa1.x);
        acc[10] += aa * bflo(qa1.y); acc[11] += aa * bfhi(qa1.y);
        acc[12] += aa * bflo(qa1.z); acc[13] += aa * bfhi(qa1.z);
        acc[14] += aa * bflo(qa1.w); acc[15] += aa * bfhi(qa1.w);
    }
    #pragma unroll
    for (int i = 0; i < 16; ++i) {
        acc[i] += __shfl_xor(acc[i], 8, 64);
        acc[i] += __shfl_xor(acc[i], 16, 64);
        acc[i] += __shfl_xor(acc[i], 32, 64);
    }
    if (es == 0) {
        float4* orow = (float4*)(outp + (size_t)n * MD + h * DV);
        #pragma unroll
        for (int i = 0; i < 4; ++i) {
            float4 o = orow[i];
            o.x += acc[i * 4 + 0]; o.y += acc[i * 4 + 1];
            o.z += acc[i * 4 + 2]; o.w += acc[i * 4 + 3];
            orow[i] = o;
        }
    }
}

// ---------------------------------------------------------------------------
extern "C" void kernel_launch(void* const* d_in, const int* in_sizes, int n_in,
                              void* d_out, int out_size, void* d_ws, size_t ws_size,
                              hipStream_t stream) {
    const float* inp  = (const float*)d_in[0];
    const int*   ei   = (const int*)d_in[1];
    const float* dist = (const float*)d_in[2];
    const float* Wv   = (const float*)d_in[4];
    const float* wsrc = (const float*)d_in[5];
    const float* wtgt = (const float*)d_in[6];
    const float* Ws   = (const float*)d_in[7];
    const float* bias = (const float*)d_in[8];

    float* outp = (float*)d_out;
    float* attn = outp + (size_t)N_NODES * MD;

    float*  wsf     = (float*)d_ws;
    float*  B       = wsf;                                     // 128 KB
    float*  vs      = B + 32768;                               // 1.6 MB
    float*  vt      = vs + N_NODES * NH;                       // 1.6 MB
    ushort* value16 = (ushort*)(vt + N_NODES * NH);            // 12.8 MB
    int4*   csr4    = (int4*)(value16 + (size_t)N_NODES * MD); // 25.6 MB
    ushort* slot16  = (ushort*)(csr4 + N_EDGES);               // 3.2 MB
    int*    deg     = (int*)(slot16 + N_EDGES);                // 200 KB
    int*    rowptr  = deg + N_NODES;                           // 50001
    int*    bsum    = rowptr + N_NODES + 1;                    // 256
    int*    boff    = bsum + 256;                              // 256

    k0_prep<<<SCAN_NBLK, 256, 0, stream>>>(Wv, Ws, B, deg);
    k_front<<<GEMM_NBLK + SLOT_NBLK, 256, 0, stream>>>(
        inp, B, bias, wsrc, wtgt, value16, vs, vt, outp, ei, deg, slot16);
    k_scan1<<<SCAN_NBLK, 256, 0, stream>>>(deg, rowptr, bsum);
    k_scan2<<<1, 256, 0, stream>>>(bsum, boff);
    k_scan3<<<SCAN_NBLK, 256, 0, stream>>>(rowptr, boff);
    k_place<<<(N_EDGES / 4 + 255) / 256, 256, 0, stream>>>(ei, rowptr, slot16,
                                                           dist, csr4);
    k_gather<<<(N_NODES + 3) / 4, 256, 0, stream>>>(csr4, rowptr, vs, vt,
                                                    value16, outp, attn);
}